// Round 1
// baseline (508.960 us; speedup 1.0000x reference)
//
#include <hip/hip_runtime.h>

// GRU4Rec fused: (1) project embedding table through W_ih once: P[V][192],
// (2) wave-per-batch-row recurrent scan with W_hh rows held in VGPRs and
//     h broadcast via v_readlane.
//
// Shapes: B=4096, T=200, H=64, V=100000. All fp32; ints arrive as int32.

#define T_SEQ 200
#define HD 64
#define VOCAB 100000
#define ROWS_PER_BLK 16   // emb rows projected per 64-thread block in phase 1

__device__ __forceinline__ float bcast(float v, int lane) {
  return __int_as_float(__builtin_amdgcn_readlane(__float_as_int(v), lane));
}

__device__ __forceinline__ float fsigmoid(float x) {
  // 1 / (1 + 2^(-x*log2e))
  float e = __builtin_amdgcn_exp2f(x * -1.442695040888963f);
  return __builtin_amdgcn_rcpf(1.0f + e);
}

__device__ __forceinline__ float ftanh(float x) {
  // tanh(x) = 2*sigmoid(2x) - 1 = 2/(1 + 2^(-2x*log2e)) - 1
  float e = __builtin_amdgcn_exp2f(x * -2.885390081777927f);
  return fmaf(2.0f, __builtin_amdgcn_rcpf(1.0f + e), -1.0f);
}

// Load rows {i, 64+i, 128+i} of a [192][64] row-major matrix into registers.
__device__ __forceinline__ void load_w3(const float* __restrict__ W, int i,
                                        float* wr, float* wz, float* wn) {
  const float4* A = reinterpret_cast<const float4*>(W + (size_t)i * HD);
  const float4* B = reinterpret_cast<const float4*>(W + (size_t)(HD + i) * HD);
  const float4* C = reinterpret_cast<const float4*>(W + (size_t)(2 * HD + i) * HD);
#pragma unroll
  for (int k4 = 0; k4 < HD / 4; ++k4) {
    float4 a = A[k4];
    wr[4 * k4 + 0] = a.x; wr[4 * k4 + 1] = a.y; wr[4 * k4 + 2] = a.z; wr[4 * k4 + 3] = a.w;
    float4 b = B[k4];
    wz[4 * k4 + 0] = b.x; wz[4 * k4 + 1] = b.y; wz[4 * k4 + 2] = b.z; wz[4 * k4 + 3] = b.w;
    float4 c = C[k4];
    wn[4 * k4 + 0] = c.x; wn[4 * k4 + 1] = c.y; wn[4 * k4 + 2] = c.z; wn[4 * k4 + 3] = c.w;
  }
}

// Phase 1: P[v][0:192] = W_ih @ emb[v]  for all v. One 64-thread block does
// ROWS_PER_BLK rows; lane i computes gates (i, 64+i, 128+i).
__global__ __launch_bounds__(64, 2) void gru_proj_kernel(
    const float* __restrict__ emb, const float* __restrict__ W_ih,
    float* __restrict__ P) {
  const int i = threadIdx.x;
  const int v0 = blockIdx.x * ROWS_PER_BLK;

  float wr[HD], wz[HD], wn[HD];
  load_w3(W_ih, i, wr, wz, wn);

  float x[ROWS_PER_BLK];
#pragma unroll
  for (int r = 0; r < ROWS_PER_BLK; ++r)
    x[r] = emb[(size_t)(v0 + r) * HD + i];   // lane i holds emb[v][i]

#pragma unroll
  for (int r = 0; r < ROWS_PER_BLK; ++r) {
    float ar = 0.f, az = 0.f, an = 0.f;
#pragma unroll
    for (int k = 0; k < HD; ++k) {
      float xk = bcast(x[r], k);
      ar = fmaf(wr[k], xk, ar);
      az = fmaf(wz[k], xk, az);
      an = fmaf(wn[k], xk, an);
    }
    float* Prow = P + (size_t)(v0 + r) * (3 * HD);
    Prow[i] = ar;
    Prow[HD + i] = az;
    Prow[2 * HD + i] = an;
  }
}

// Phase 2: recurrent scan. One wave per batch row; lane i = hidden index.
__global__ __launch_bounds__(64, 2) void gru_scan_kernel(
    const int* __restrict__ seq_token, const int* __restrict__ seq_pos,
    const float* __restrict__ P, const float* __restrict__ W_hh,
    float* __restrict__ out) {
  const int i = threadIdx.x;
  const int b = blockIdx.x;

  int L = seq_pos[b];
  L = L < 1 ? 1 : (L > T_SEQ ? T_SEQ : L);

  float wr[HD], wz[HD], wn[HD];
  load_w3(W_hh, i, wr, wz, wn);

  const int* tok = seq_token + (size_t)b * T_SEQ;

  // Prefetch P row for t=0 (L >= 1 always).
  {
    int t0 = tok[0];
    const float* Pr = P + (size_t)t0 * (3 * HD);
    // fallthrough into loop-carried pr/pz/pn
    // (initialized below)
    (void)Pr;
  }
  int t0 = tok[0];
  const float* P0 = P + (size_t)t0 * (3 * HD);
  float pr = P0[i], pz = P0[HD + i], pn = P0[2 * HD + i];

  float h = 0.f;
  for (int t = 0; t < L; ++t) {
    // Prefetch next step's projected-input row (wave-uniform branch).
    float nr = 0.f, nz = 0.f, nn = 0.f;
    if (t + 1 < L) {
      int tn = tok[t + 1];
      const float* Pn = P + (size_t)tn * (3 * HD);
      nr = Pn[i]; nz = Pn[HD + i]; nn = Pn[2 * HD + i];
    }

    // gh = W_hh rows {i, 64+i, 128+i} dot h; h[k] broadcast via readlane.
    float ghr = 0.f, ghz = 0.f, ghn = 0.f;
#pragma unroll
    for (int k = 0; k < HD; ++k) {
      float hk = bcast(h, k);
      ghr = fmaf(wr[k], hk, ghr);
      ghz = fmaf(wz[k], hk, ghz);
      ghn = fmaf(wn[k], hk, ghn);
    }

    float r = fsigmoid(pr + ghr);
    float z = fsigmoid(pz + ghz);
    float n = ftanh(fmaf(r, ghn, pn));
    h = fmaf(z, h - n, n);   // (1-z)*n + z*h

    pr = nr; pz = nz; pn = nn;
  }

  out[(size_t)b * HD + i] = h;
}

extern "C" void kernel_launch(void* const* d_in, const int* in_sizes, int n_in,
                              void* d_out, int out_size, void* d_ws, size_t ws_size,
                              hipStream_t stream) {
  const int* seq_token = (const int*)d_in[0];   // [B, T] int32
  const int* seq_pos   = (const int*)d_in[1];   // [B] int32
  const float* emb     = (const float*)d_in[2]; // [V, H]
  const float* W_ih    = (const float*)d_in[3]; // [3H, H]
  const float* W_hh    = (const float*)d_in[4]; // [3H, H]
  float* out = (float*)d_out;                   // [B, H]

  const int B = in_sizes[1];                    // 4096

  // Workspace: projected embedding table P[V][3H] = 76.8 MB.
  float* P = (float*)d_ws;

  gru_proj_kernel<<<VOCAB / ROWS_PER_BLK, 64, 0, stream>>>(emb, W_ih, P);
  gru_scan_kernel<<<B, 64, 0, stream>>>(seq_token, seq_pos, P, W_hh, out);
}

// Round 2
// 467.873 us; speedup vs baseline: 1.0878x; 1.0878x over previous
//
#include <hip/hip_runtime.h>

// GRU4Rec fused, round 2: weights held as ext_vector_type(16) SSA values
// (no allocas -> guaranteed VGPR residency; round 1's 64-float local arrays
// were demoted to scratch: VGPR_Count=104 < 192 weights).
//
// Phase 1: P[v][0:192] = W_ih @ emb[v] for all v (token-projection table).
// Phase 2: wave-per-batch-row recurrent scan; W_hh rows in VGPRs,
//          h broadcast via v_readlane.
//
// Shapes: B=4096, T=200, H=64, V=100000. All fp32; ints arrive as int32.

#define T_SEQ 200
#define HD 64
#define VOCAB 100000
#define ROWS_PER_BLK 16

typedef float v16f __attribute__((ext_vector_type(16)));

__device__ __forceinline__ float bcast(float v, int lane) {
  return __int_as_float(__builtin_amdgcn_readlane(__float_as_int(v), lane));
}

__device__ __forceinline__ float fsigmoid(float x) {
  float e = __builtin_amdgcn_exp2f(x * -1.442695040888963f);
  return __builtin_amdgcn_rcpf(1.0f + e);
}

__device__ __forceinline__ float ftanh(float x) {
  float e = __builtin_amdgcn_exp2f(x * -2.885390081777927f);
  return fmaf(2.0f, __builtin_amdgcn_rcpf(1.0f + e), -1.0f);
}

// Load row i, row 64+i, row 128+i of a [192][64] row-major matrix into
// 4-chunk vector registers (each chunk = 16 floats = 64 B, aligned).
#define LOAD_W3(W, i, wr, wz, wn)                                         \
  do {                                                                    \
    const v16f* A = reinterpret_cast<const v16f*>((W) + (size_t)(i)*HD);  \
    const v16f* Bp = reinterpret_cast<const v16f*>((W) + (size_t)(HD + (i)) * HD); \
    const v16f* C = reinterpret_cast<const v16f*>((W) + (size_t)(2 * HD + (i)) * HD); \
    wr[0] = A[0]; wr[1] = A[1]; wr[2] = A[2]; wr[3] = A[3];               \
    wz[0] = Bp[0]; wz[1] = Bp[1]; wz[2] = Bp[2]; wz[3] = Bp[3];           \
    wn[0] = C[0]; wn[1] = C[1]; wn[2] = C[2]; wn[3] = C[3];               \
  } while (0)

// ---------------------------------------------------------------- phase 1
__global__ __launch_bounds__(64, 2) void gru_proj_kernel(
    const float* __restrict__ emb, const float* __restrict__ W_ih,
    float* __restrict__ P) {
  const int i = threadIdx.x;
  const int v0 = blockIdx.x * ROWS_PER_BLK;

  v16f wr[4], wz[4], wn[4];
  LOAD_W3(W_ih, i, wr, wz, wn);

  float x[ROWS_PER_BLK];
#pragma unroll
  for (int r = 0; r < ROWS_PER_BLK; ++r)
    x[r] = emb[(size_t)(v0 + r) * HD + i];  // lane i holds emb[v][i]

#pragma unroll
  for (int r = 0; r < ROWS_PER_BLK; ++r) {
    float ar0 = 0.f, az0 = 0.f, an0 = 0.f;
    float ar1 = 0.f, az1 = 0.f, an1 = 0.f;
#pragma unroll
    for (int q = 0; q < 4; ++q) {
#pragma unroll
      for (int j = 0; j < 16; ++j) {
        float xk = bcast(x[r], 16 * q + j);
        if (q & 1) {
          ar1 = fmaf(wr[q][j], xk, ar1);
          az1 = fmaf(wz[q][j], xk, az1);
          an1 = fmaf(wn[q][j], xk, an1);
        } else {
          ar0 = fmaf(wr[q][j], xk, ar0);
          az0 = fmaf(wz[q][j], xk, az0);
          an0 = fmaf(wn[q][j], xk, an0);
        }
      }
    }
    float* Prow = P + (size_t)(v0 + r) * (3 * HD);
    Prow[i] = ar0 + ar1;
    Prow[HD + i] = az0 + az1;
    Prow[2 * HD + i] = an0 + an1;
  }
}

// ---------------------------------------------------------------- phase 2
__global__ __launch_bounds__(64, 2) void gru_scan_kernel(
    const int* __restrict__ seq_token, const int* __restrict__ seq_pos,
    const float* __restrict__ P, const float* __restrict__ W_hh,
    float* __restrict__ out) {
  const int i = threadIdx.x;
  const int b = blockIdx.x;

  int L = seq_pos[b];
  L = L < 1 ? 1 : (L > T_SEQ ? T_SEQ : L);

  v16f wr[4], wz[4], wn[4];
  LOAD_W3(W_hh, i, wr, wz, wn);

  const int* tok = seq_token + (size_t)b * T_SEQ;

  int t0 = tok[0];
  const float* P0 = P + (size_t)t0 * (3 * HD);
  float pr = P0[i], pz = P0[HD + i], pn = P0[2 * HD + i];

  float h = 0.f;
  for (int t = 0; t < L; ++t) {
    // Prefetch next step's projected-input row (wave-uniform branch).
    float nr = 0.f, nz = 0.f, nn = 0.f;
    if (t + 1 < L) {
      int tn = tok[t + 1];
      const float* Pn = P + (size_t)tn * (3 * HD);
      nr = Pn[i]; nz = Pn[HD + i]; nn = Pn[2 * HD + i];
    }

    // gh = W_hh rows {i, 64+i, 128+i} . h ; h[k] broadcast via readlane.
    float ghr0 = 0.f, ghz0 = 0.f, ghn0 = 0.f;
    float ghr1 = 0.f, ghz1 = 0.f, ghn1 = 0.f;
#pragma unroll
    for (int q = 0; q < 4; ++q) {
#pragma unroll
      for (int j = 0; j < 16; ++j) {
        float hk = bcast(h, 16 * q + j);
        if (q & 1) {
          ghr1 = fmaf(wr[q][j], hk, ghr1);
          ghz1 = fmaf(wz[q][j], hk, ghz1);
          ghn1 = fmaf(wn[q][j], hk, ghn1);
        } else {
          ghr0 = fmaf(wr[q][j], hk, ghr0);
          ghz0 = fmaf(wz[q][j], hk, ghz0);
          ghn0 = fmaf(wn[q][j], hk, ghn0);
        }
      }
    }

    float r = fsigmoid(pr + ghr0 + ghr1);
    float z = fsigmoid(pz + ghz0 + ghz1);
    float n = ftanh(fmaf(r, ghn0 + ghn1, pn));
    h = fmaf(z, h - n, n);  // (1-z)*n + z*h

    pr = nr; pz = nz; pn = nn;
  }

  out[(size_t)b * HD + i] = h;
}

extern "C" void kernel_launch(void* const* d_in, const int* in_sizes, int n_in,
                              void* d_out, int out_size, void* d_ws, size_t ws_size,
                              hipStream_t stream) {
  const int* seq_token = (const int*)d_in[0];   // [B, T] int32
  const int* seq_pos   = (const int*)d_in[1];   // [B] int32
  const float* emb     = (const float*)d_in[2]; // [V, H]
  const float* W_ih    = (const float*)d_in[3]; // [3H, H]
  const float* W_hh    = (const float*)d_in[4]; // [3H, H]
  float* out = (float*)d_out;                   // [B, H]

  const int B = in_sizes[1];                    // 4096

  float* P = (float*)d_ws;                      // P[V][3H] = 76.8 MB

  gru_proj_kernel<<<VOCAB / ROWS_PER_BLK, 64, 0, stream>>>(emb, W_ih, P);
  gru_scan_kernel<<<B, 64, 0, stream>>>(seq_token, seq_pos, P, W_hh, out);
}